// Round 1
// baseline (270.684 us; speedup 1.0000x reference)
//
#include <hip/hip_runtime.h>

// DistoLayer: logits[m*K+k, c] for
//   n_i = x[dst] @ Wq                       [M, D]
//   A[m,d',h] = sum_d n_i[m,d] Wk[d',h*64+d]   (reassociated; / sqrt(D) folded in)
//   pair[m,k,h] = sum_d' x[src[m,k],d'] A[m,d',h]
//   hidden = relu(pair @ Wp1); logits = hidden @ Wp2
//
// N=100000, M=10000, K=32, D=64, H=8, C=64. All f32; indices int32.

#define Mm 10000
#define Kk 32
#define Dd 64
#define Hh 8
#define Cc 64

constexpr int WAVES = 4;       // m's per block (one wave each)
constexpr int PAD = 68;        // padded row stride (floats): 68%32=4 spreads banks,
                               // 68*4=272 B keeps 16 B alignment for float4

__global__ __launch_bounds__(256) void disto_kernel(
    const float* __restrict__ x,
    const int*   __restrict__ src_idx,
    const int*   __restrict__ dst_idx,
    const float* __restrict__ Wq,
    const float* __restrict__ Wk,
    const float* __restrict__ Wp1,
    const float* __restrict__ Wp2,
    float* __restrict__ out)
{
    __shared__ float ni_lds[WAVES][Dd];        // n_i per wave
    __shared__ float A_lds[WAVES][Hh][PAD];    // A[w][h][d'], pre-scaled by 0.125
    __shared__ float xs_lds[WAVES][8][PAD];    // 8 staged src rows per wave
    __shared__ float wp2_lds[Hh * Cc];         // 512 floats

    const int t = threadIdx.x;
    const int w = t >> 6;                      // wave id = which m
    const int l = t & 63;                      // lane
    const int m = blockIdx.x * WAVES + w;      // 2500*4 = 10000 exactly

    // stage Wp2 once (128 float4 loads)
    if (t < 128) ((float4*)wp2_lds)[t] = ((const float4*)Wp2)[t];

    // ---- phase 1: n_i[m, l] = sum_d' x[dst,d'] * Wq[d',l] ----
    const int dst = dst_idx[m];
    float xd = x[(size_t)dst * Dd + l];
    float acc1 = 0.f;
    #pragma unroll
    for (int dp = 0; dp < Dd; ++dp) {
        float xv = __shfl(xd, dp, 64);
        acc1 = fmaf(xv, Wq[dp * Dd + l], acc1);   // coalesced across lanes
    }
    ni_lds[w][l] = acc1;

    __syncthreads();

    // ---- phase 2: A_lds[w][h][l] = 0.125 * sum_d ni[d] * Wk[l*512 + h*64 + d] ----
    {
        const float4* ni4 = (const float4*)ni_lds[w];
        const float4* wkrow = (const float4*)(Wk + (size_t)l * (Dd * Hh));
        #pragma unroll
        for (int h = 0; h < Hh; ++h) {
            float a = 0.f;
            #pragma unroll
            for (int d4 = 0; d4 < Dd / 4; ++d4) {
                float4 nv = ni4[d4];                    // LDS broadcast read
                float4 wv = wkrow[h * (Dd / 4) + d4];   // per-lane row stream (L1/L2)
                a = fmaf(nv.x, wv.x, a);
                a = fmaf(nv.y, wv.y, a);
                a = fmaf(nv.z, wv.z, a);
                a = fmaf(nv.w, wv.w, a);
            }
            A_lds[w][h][l] = a * 0.125f;   // fold 1/sqrt(64)
        }
    }

    // per-lane roles for phase 3
    const int h_role = l & 7;     // which head
    const int k8 = l >> 3;        // which of 8 k's in the chunk
    float wp1r[8];
    #pragma unroll
    for (int j = 0; j < 8; ++j) wp1r[j] = Wp1[h_role * Hh + j];

    __syncthreads();

    // ---- phase 3: 4 chunks of 8 k each ----
    for (int kc = 0; kc < 4; ++kc) {
        // stage 8 gathered src rows (128 float4 tasks over 2 passes)
        #pragma unroll
        for (int p = 0; p < 2; ++p) {
            int task = p * 64 + l;
            int r = task >> 4;       // row 0..7
            int j = task & 15;       // float4 within row
            int idx = src_idx[m * Kk + kc * 8 + r];
            float4 v = ((const float4*)x)[(size_t)idx * (Dd / 4) + j];
            *(float4*)&xs_lds[w][r][j * 4] = v;
        }
        __syncthreads();

        // pair[m, kc*8+k8, h_role] = dot64(xs[k8], A[:,h_role])  (both LDS, conflict-free)
        float pair = 0.f;
        {
            const float4* xsr = (const float4*)xs_lds[w][k8];
            const float4* ar  = (const float4*)A_lds[w][h_role];
            #pragma unroll
            for (int d4 = 0; d4 < Dd / 4; ++d4) {
                float4 xv = xsr[d4];
                float4 av = ar[d4];
                pair = fmaf(xv.x, av.x, pair);
                pair = fmaf(xv.y, av.y, pair);
                pair = fmaf(xv.z, av.z, pair);
                pair = fmaf(xv.w, av.w, pair);
            }
        }

        // hidden[j] = relu(sum_h pair_h * Wp1[h,j]) — butterfly over the 8-lane h-group
        float hid[8];
        #pragma unroll
        for (int j = 0; j < 8; ++j) hid[j] = pair * wp1r[j];
        #pragma unroll
        for (int s = 1; s < 8; s <<= 1) {
            #pragma unroll
            for (int j = 0; j < 8; ++j)
                hid[j] += __shfl_xor(hid[j], s, 64);
        }
        #pragma unroll
        for (int j = 0; j < 8; ++j) hid[j] = fmaxf(hid[j], 0.f);

        // logits[c = h_role*8 + jj] = sum_h' hid[h'] * Wp2[h', c]
        float lg[8] = {0,0,0,0,0,0,0,0};
        #pragma unroll
        for (int hp = 0; hp < 8; ++hp) {
            const float* wrow = &wp2_lds[hp * Cc + h_role * 8];
            float4 wa = *(const float4*)wrow;
            float4 wb = *(const float4*)(wrow + 4);
            lg[0] = fmaf(hid[hp], wa.x, lg[0]);
            lg[1] = fmaf(hid[hp], wa.y, lg[1]);
            lg[2] = fmaf(hid[hp], wa.z, lg[2]);
            lg[3] = fmaf(hid[hp], wa.w, lg[3]);
            lg[4] = fmaf(hid[hp], wb.x, lg[4]);
            lg[5] = fmaf(hid[hp], wb.y, lg[5]);
            lg[6] = fmaf(hid[hp], wb.z, lg[6]);
            lg[7] = fmaf(hid[hp], wb.w, lg[7]);
        }
        size_t row = (size_t)(m * Kk + kc * 8 + k8);
        float4* o4 = (float4*)(out + row * Cc + h_role * 8);
        o4[0] = make_float4(lg[0], lg[1], lg[2], lg[3]);
        o4[1] = make_float4(lg[4], lg[5], lg[6], lg[7]);

        __syncthreads();   // xs_lds reuse next chunk
    }
}

extern "C" void kernel_launch(void* const* d_in, const int* in_sizes, int n_in,
                              void* d_out, int out_size, void* d_ws, size_t ws_size,
                              hipStream_t stream) {
    const float* x       = (const float*)d_in[0];
    const int*   src_idx = (const int*)  d_in[1];
    const int*   dst_idx = (const int*)  d_in[2];
    const float* Wq      = (const float*)d_in[3];
    const float* Wk      = (const float*)d_in[4];
    const float* Wp1     = (const float*)d_in[5];
    const float* Wp2     = (const float*)d_in[6];
    float* out = (float*)d_out;

    dim3 grid(Mm / WAVES);   // 2500
    dim3 block(256);
    disto_kernel<<<grid, block, 0, stream>>>(x, src_idx, dst_idx, Wq, Wk, Wp1, Wp2, out);
}

// Round 2
// 156.388 us; speedup vs baseline: 1.7309x; 1.7309x over previous
//
#include <hip/hip_runtime.h>

// DistoLayer, reassociated:
//   n_i[m]      = x[dst[m]] @ Wq                                  [M, D]
//   A[m,h,d']   = (1/8) * sum_d n_i[m,d] * Wk[d', h*64+d]         [M, H, D]
//   pair[m,k,h] = sum_d' x[src[m,k], d'] * A[m,h,d']
//   hidden = relu(pair @ Wp1); logits = hidden @ Wp2              [M*K, C]
//
// N=100000, M=10000, K=32, D=64, H=8, C=64. All f32; indices int32.
// Split into two kernels: A-builder (batched m, shares Wk staging) and
// per-m consumer (high occupancy). A lives in d_ws (20.48 MB).

#define Mm 10000
#define Kk 32
#define Dd 64
#define Hh 8
#define Cc 64

constexpr int MA = 16;            // m's per block in kernel A
constexpr size_t A_BYTES = (size_t)Mm * Hh * Dd * sizeof(float);  // 20.48 MB

// ---------------------------------------------------------------- kernel A
__global__ __launch_bounds__(256) void disto_A(
    const float* __restrict__ x,
    const int*   __restrict__ dst_idx,
    const float* __restrict__ Wq,
    const float* __restrict__ Wk,
    float* __restrict__ A)
{
    __shared__ float xs[MA][68];   // gathered dst rows (pad 68: float4-aligned, bank-spread)
    __shared__ float ni[MA][68];   // n_i
    __shared__ float wk[Dd][68];   // one h-chunk of Wk: wk[d'][d] (natural layout)

    const int t  = threadIdx.x;
    const int m0 = blockIdx.x * MA;
    const int mi = t >> 4;         // 0..15
    const int j  = t & 15;         // 0..15

    // gather 16 dst rows (one float4/thread, coalesced in 256B segments)
    {
        int idx = dst_idx[m0 + mi];
        float4 v = ((const float4*)x)[(size_t)idx * 16 + j];
        *(float4*)&xs[mi][j * 4] = v;
    }
    __syncthreads();

    // n_i[mi][4j..4j+3] = sum_d xs[mi][d] * Wq[d][4j..4j+3]
    {
        float4 acc = make_float4(0.f, 0.f, 0.f, 0.f);
        #pragma unroll
        for (int d = 0; d < Dd; ++d) {
            float  xv = xs[mi][d];                       // 4-addr broadcast
            float4 wv = ((const float4*)Wq)[d * 16 + j]; // 256B, L1-resident
            acc.x = fmaf(xv, wv.x, acc.x);
            acc.y = fmaf(xv, wv.y, acc.y);
            acc.z = fmaf(xv, wv.z, acc.z);
            acc.w = fmaf(xv, wv.w, acc.w);
        }
        *(float4*)&ni[mi][j * 4] = acc;
    }
    __syncthreads();

    for (int h = 0; h < Hh; ++h) {
        // stage wk[d'][d] = Wk[d'][h*64+d], coalesced float4, natural layout
        #pragma unroll
        for (int p = 0; p < 4; ++p) {
            int task = p * 256 + t;
            int dp = task >> 4;    // 0..63
            int q  = task & 15;
            float4 v = ((const float4*)Wk)[(size_t)dp * 128 + h * 16 + q];
            *(float4*)&wk[dp][q * 4] = v;
        }
        __syncthreads();

        // thread (mi, j) reduces over d for d' = rep*16 + j
        float res[4];
        #pragma unroll
        for (int rep = 0; rep < 4; ++rep) {
            const int dp = rep * 16 + j;
            const float4* wr = (const float4*)wk[dp];
            const float4* nr = (const float4*)ni[mi];
            float acc = 0.f;
            #pragma unroll
            for (int d4 = 0; d4 < 16; ++d4) {
                float4 nv = nr[d4];   // 4-addr broadcast
                float4 wv = wr[d4];   // 16-addr b128, conflict-free
                acc = fmaf(nv.x, wv.x, acc);
                acc = fmaf(nv.y, wv.y, acc);
                acc = fmaf(nv.z, wv.z, acc);
                acc = fmaf(nv.w, wv.w, acc);
            }
            res[rep] = acc * 0.125f;   // fold 1/sqrt(D)
        }
        #pragma unroll
        for (int rep = 0; rep < 4; ++rep)
            A[(size_t)(m0 + mi) * 512 + h * 64 + rep * 16 + j] = res[rep];
        __syncthreads();
    }
}

// ---------------------------------------------------------------- kernel B
__global__ __launch_bounds__(256) void disto_B(
    const float* __restrict__ x,
    const int*   __restrict__ src_idx,
    const float* __restrict__ A,
    const float* __restrict__ Wp1,
    const float* __restrict__ Wp2,
    float* __restrict__ out)
{
    __shared__ float a_lds[Hh][68];   // A[m] as [h][d']
    __shared__ float xs[Kk][68];      // 32 gathered src rows
    __shared__ float wp2[Hh * Cc];

    const int t = threadIdx.x;
    const int m = blockIdx.x;
    const int w = t >> 6;             // wave: handles k = w*8 + k8
    const int l = t & 63;

    if (t < 128) {                    // waves 0-1: stage A[m]
        float4 v = ((const float4*)A)[(size_t)m * 128 + t];
        *(float4*)&a_lds[t >> 4][(t & 15) * 4] = v;
    } else {                          // waves 2-3: stage Wp2
        ((float4*)wp2)[t - 128] = ((const float4*)Wp2)[t - 128];
    }
    // gather 32 src rows (512 float4 tasks)
    #pragma unroll
    for (int p = 0; p < 2; ++p) {
        int task = p * 256 + t;
        int r = task >> 4;            // 0..31
        int q = task & 15;
        int idx = src_idx[m * Kk + r];
        float4 v = ((const float4*)x)[(size_t)idx * 16 + q];
        *(float4*)&xs[r][q * 4] = v;
    }

    const int h_role = l & 7;
    const int k8     = l >> 3;
    float wp1r[8];
    #pragma unroll
    for (int jj = 0; jj < 8; ++jj) wp1r[jj] = Wp1[h_role * Hh + jj];

    __syncthreads();

    // pair = dot64(xs[k], a_lds[h_role]); both LDS reads broadcast/conflict-free
    const int k = w * 8 + k8;
    float pair = 0.f;
    {
        const float4* xr = (const float4*)xs[k];
        const float4* ar = (const float4*)a_lds[h_role];
        #pragma unroll
        for (int d4 = 0; d4 < 16; ++d4) {
            float4 xv = xr[d4];
            float4 av = ar[d4];
            pair = fmaf(xv.x, av.x, pair);
            pair = fmaf(xv.y, av.y, pair);
            pair = fmaf(xv.z, av.z, pair);
            pair = fmaf(xv.w, av.w, pair);
        }
    }

    // hidden = relu(pair @ Wp1): butterfly over the 8-lane h-group
    float hid[8];
    #pragma unroll
    for (int jj = 0; jj < 8; ++jj) hid[jj] = pair * wp1r[jj];
    #pragma unroll
    for (int s = 1; s < 8; s <<= 1) {
        #pragma unroll
        for (int jj = 0; jj < 8; ++jj)
            hid[jj] += __shfl_xor(hid[jj], s, 64);
    }
    #pragma unroll
    for (int jj = 0; jj < 8; ++jj) hid[jj] = fmaxf(hid[jj], 0.f);

    // logits[c = h_role*8 + cc] = sum_hp hid[hp] * Wp2[hp][c]
    float lg[8] = {0,0,0,0,0,0,0,0};
    #pragma unroll
    for (int hp = 0; hp < 8; ++hp) {
        const float* wrow = &wp2[hp * Cc + h_role * 8];
        float4 wa = *(const float4*)wrow;
        float4 wb = *(const float4*)(wrow + 4);
        lg[0] = fmaf(hid[hp], wa.x, lg[0]);
        lg[1] = fmaf(hid[hp], wa.y, lg[1]);
        lg[2] = fmaf(hid[hp], wa.z, lg[2]);
        lg[3] = fmaf(hid[hp], wa.w, lg[3]);
        lg[4] = fmaf(hid[hp], wb.x, lg[4]);
        lg[5] = fmaf(hid[hp], wb.y, lg[5]);
        lg[6] = fmaf(hid[hp], wb.z, lg[6]);
        lg[7] = fmaf(hid[hp], wb.w, lg[7]);
    }
    size_t row = (size_t)m * Kk + k;
    float4* o4 = (float4*)(out + row * Cc + h_role * 8);
    o4[0] = make_float4(lg[0], lg[1], lg[2], lg[3]);
    o4[1] = make_float4(lg[4], lg[5], lg[6], lg[7]);
}

// ------------------------------------------------- fallback fused kernel
// (round-1 version; used only if ws_size can't hold A)
constexpr int WAVES = 4;
constexpr int PAD = 68;

__global__ __launch_bounds__(256) void disto_fused(
    const float* __restrict__ x,
    const int*   __restrict__ src_idx,
    const int*   __restrict__ dst_idx,
    const float* __restrict__ Wq,
    const float* __restrict__ Wk,
    const float* __restrict__ Wp1,
    const float* __restrict__ Wp2,
    float* __restrict__ out)
{
    __shared__ float ni_lds[WAVES][Dd];
    __shared__ float A_lds[WAVES][Hh][PAD];
    __shared__ float xs_lds[WAVES][8][PAD];
    __shared__ float wp2_lds[Hh * Cc];

    const int t = threadIdx.x;
    const int w = t >> 6;
    const int l = t & 63;
    const int m = blockIdx.x * WAVES + w;

    if (t < 128) ((float4*)wp2_lds)[t] = ((const float4*)Wp2)[t];

    const int dst = dst_idx[m];
    float xd = x[(size_t)dst * Dd + l];
    float acc1 = 0.f;
    #pragma unroll
    for (int dp = 0; dp < Dd; ++dp) {
        float xv = __shfl(xd, dp, 64);
        acc1 = fmaf(xv, Wq[dp * Dd + l], acc1);
    }
    ni_lds[w][l] = acc1;
    __syncthreads();
    {
        const float4* ni4 = (const float4*)ni_lds[w];
        const float4* wkrow = (const float4*)(Wk + (size_t)l * (Dd * Hh));
        #pragma unroll
        for (int h = 0; h < Hh; ++h) {
            float a = 0.f;
            #pragma unroll
            for (int d4 = 0; d4 < Dd / 4; ++d4) {
                float4 nv = ni4[d4];
                float4 wv = wkrow[h * (Dd / 4) + d4];
                a = fmaf(nv.x, wv.x, a);
                a = fmaf(nv.y, wv.y, a);
                a = fmaf(nv.z, wv.z, a);
                a = fmaf(nv.w, wv.w, a);
            }
            A_lds[w][h][l] = a * 0.125f;
        }
    }
    const int h_role = l & 7;
    const int k8 = l >> 3;
    float wp1r[8];
    #pragma unroll
    for (int j = 0; j < 8; ++j) wp1r[j] = Wp1[h_role * Hh + j];
    __syncthreads();

    for (int kc = 0; kc < 4; ++kc) {
        #pragma unroll
        for (int p = 0; p < 2; ++p) {
            int task = p * 64 + l;
            int r = task >> 4;
            int j = task & 15;
            int idx = src_idx[m * Kk + kc * 8 + r];
            float4 v = ((const float4*)x)[(size_t)idx * (Dd / 4) + j];
            *(float4*)&xs_lds[w][r][j * 4] = v;
        }
        __syncthreads();
        float pair = 0.f;
        {
            const float4* xsr = (const float4*)xs_lds[w][k8];
            const float4* ar  = (const float4*)A_lds[w][h_role];
            #pragma unroll
            for (int d4 = 0; d4 < Dd / 4; ++d4) {
                float4 xv = xsr[d4];
                float4 av = ar[d4];
                pair = fmaf(xv.x, av.x, pair);
                pair = fmaf(xv.y, av.y, pair);
                pair = fmaf(xv.z, av.z, pair);
                pair = fmaf(xv.w, av.w, pair);
            }
        }
        float hid[8];
        #pragma unroll
        for (int j = 0; j < 8; ++j) hid[j] = pair * wp1r[j];
        #pragma unroll
        for (int s = 1; s < 8; s <<= 1) {
            #pragma unroll
            for (int j = 0; j < 8; ++j)
                hid[j] += __shfl_xor(hid[j], s, 64);
        }
        #pragma unroll
        for (int j = 0; j < 8; ++j) hid[j] = fmaxf(hid[j], 0.f);
        float lg[8] = {0,0,0,0,0,0,0,0};
        #pragma unroll
        for (int hp = 0; hp < 8; ++hp) {
            const float* wrow = &wp2_lds[hp * Cc + h_role * 8];
            float4 wa = *(const float4*)wrow;
            float4 wb = *(const float4*)(wrow + 4);
            lg[0] = fmaf(hid[hp], wa.x, lg[0]);
            lg[1] = fmaf(hid[hp], wa.y, lg[1]);
            lg[2] = fmaf(hid[hp], wa.z, lg[2]);
            lg[3] = fmaf(hid[hp], wa.w, lg[3]);
            lg[4] = fmaf(hid[hp], wb.x, lg[4]);
            lg[5] = fmaf(hid[hp], wb.y, lg[5]);
            lg[6] = fmaf(hid[hp], wb.z, lg[6]);
            lg[7] = fmaf(hid[hp], wb.w, lg[7]);
        }
        size_t row = (size_t)(m * Kk + kc * 8 + k8);
        float4* o4 = (float4*)(out + row * Cc + h_role * 8);
        o4[0] = make_float4(lg[0], lg[1], lg[2], lg[3]);
        o4[1] = make_float4(lg[4], lg[5], lg[6], lg[7]);
        __syncthreads();
    }
}

extern "C" void kernel_launch(void* const* d_in, const int* in_sizes, int n_in,
                              void* d_out, int out_size, void* d_ws, size_t ws_size,
                              hipStream_t stream) {
    const float* x       = (const float*)d_in[0];
    const int*   src_idx = (const int*)  d_in[1];
    const int*   dst_idx = (const int*)  d_in[2];
    const float* Wq      = (const float*)d_in[3];
    const float* Wk      = (const float*)d_in[4];
    const float* Wp1     = (const float*)d_in[5];
    const float* Wp2     = (const float*)d_in[6];
    float* out = (float*)d_out;

    if (ws_size >= A_BYTES) {
        float* A = (float*)d_ws;
        disto_A<<<dim3(Mm / MA), dim3(256), 0, stream>>>(x, dst_idx, Wq, Wk, A);
        disto_B<<<dim3(Mm), dim3(256), 0, stream>>>(x, src_idx, A, Wp1, Wp2, out);
    } else {
        disto_fused<<<dim3(Mm / WAVES), dim3(256), 0, stream>>>(
            x, src_idx, dst_idx, Wq, Wk, Wp1, Wp2, out);
    }
}